// Round 3
// baseline (2135.058 us; speedup 1.0000x reference)
//
#include <hip/hip_runtime.h>
#include <math.h>

#define Hn   256
#define En   128
#define Vn   256
#define TPn  32
#define BTn  2048
#define NSEQ 16
#define NWG  (BTn / NSEQ)   // 128 workgroups, 16 waves each
#define NT   1024

typedef __attribute__((ext_vector_type(8))) short bf8v;   // 8 bf16 = one MFMA A/B frag
typedef __attribute__((ext_vector_type(4))) float f4v;    // MFMA C/D frag

__device__ __forceinline__ unsigned short bf_hi(float x) {
    unsigned u = __float_as_uint(x);
    return (unsigned short)((u + 0x7FFFu + ((u >> 16) & 1u)) >> 16);  // RNE
}
__device__ __forceinline__ float bf_f(unsigned short h) {
    return __uint_as_float(((unsigned)h) << 16);
}
__device__ __forceinline__ float sigf(float x) { return 1.0f / (1.0f + expf(-x)); }
__device__ __forceinline__ unsigned long long amax_key(float sc, int v) {
    unsigned fb = __float_as_uint(sc);
    fb = (fb & 0x80000000u) ? ~fb : (fb | 0x80000000u);   // order-preserving
    return ((unsigned long long)fb << 32) | (unsigned)(Vn - 1 - v);  // first-idx tie-break
}

// ---------------- precompute kernels ----------------

// Ptu[v*256+u] = float4{i,f,g,o} preact contribution: emb[v]@Wih[g*256+u]^T + bih + bhh
__global__ void make_ptab(float4* __restrict__ Pp, const float* __restrict__ emb,
                          const float* __restrict__ Wih, const float* __restrict__ bih,
                          const float* __restrict__ bhh) {
    int v = blockIdx.x, u = threadIdx.x;
    __shared__ __align__(16) float es[En];
    if (u < En) es[u] = emb[v * En + u];
    __syncthreads();
    float a[4];
#pragma unroll
    for (int g = 0; g < 4; ++g) {
        int r = g * Hn + u;
        float acc = bih[r] + bhh[r];
        const float4* w4 = (const float4*)(Wih + r * En);
        const float4* e4 = (const float4*)es;
        for (int k = 0; k < En / 4; ++k) {
            float4 w = w4[k], x = e4[k];
            acc = fmaf(w.x, x.x, fmaf(w.y, x.y, fmaf(w.z, x.z, fmaf(w.w, x.w, acc))));
        }
        a[g] = acc;
    }
    Pp[v * Hn + u] = make_float4(a[0], a[1], a[2], a[3]);
}

// Pack Whh into MFMA A-frag order with gate-interleaved rows rho = 4*u + g.
// A-frag (16x16x32): lane holds A[m=lane&15][k=(lane>>4)*8+j], j=0..7.
// idx -> j(3) | lane(6) | kt(3) | mt : Whi/Wlo bf16 hi/lo split.
__global__ void pack_w(unsigned short* __restrict__ Whi, unsigned short* __restrict__ Wlo,
                       const float* __restrict__ W) {   // W: [1024][256] (gate-major rows)
    int idx = blockIdx.x * 256 + threadIdx.x;           // 262144 entries
    int j = idx & 7, lane = (idx >> 3) & 63, kt = (idx >> 9) & 7, mt = idx >> 12;
    int rho = mt * 16 + (lane & 15);
    int e = kt * 32 + ((lane >> 4) << 3) + j;
    int u = rho >> 2, g = rho & 3;
    float x = W[(g * Hn + u) * Hn + e];
    unsigned short h = bf_hi(x);
    Whi[idx] = h;
    Wlo[idx] = bf_hi(x - bf_f(h));
}

// Pack fc_W (rows = vocab, no remap) into A-frag order. 65536 entries.
__global__ void pack_fcw(unsigned short* __restrict__ Fhi, unsigned short* __restrict__ Flo,
                         const float* __restrict__ W) {  // [256][256]
    int idx = blockIdx.x * 256 + threadIdx.x;
    int j = idx & 7, lane = (idx >> 3) & 63, kt = (idx >> 9) & 7, mt = idx >> 12;
    int v = mt * 16 + (lane & 15);
    int e = kt * 32 + ((lane >> 4) << 3) + j;
    float x = W[v * Hn + e];
    unsigned short h = bf_hi(x);
    Fhi[idx] = h;
    Flo[idx] = bf_hi(x - bf_f(h));
}

// ---------------- encoder ----------------
// 128 WGs x 1024 thr (16 waves). Wave wv owns units [16wv,16wv+16): acc reg i = gate i.
__global__ __launch_bounds__(NT) void enc_kernel(
    const bf8v* __restrict__ Ahi, const bf8v* __restrict__ Alo,
    const float4* __restrict__ Ptu, const int* __restrict__ phon,
    const int* __restrict__ lens, float* __restrict__ h0dec) {
    const int tid = threadIdx.x, wg = blockIdx.x;
    const int ln = tid & 63, wv = tid >> 6;
    const int q = ln >> 4, s = ln & 15;
    __shared__ __align__(16) unsigned short hBhi[2][8][64][8];   // B-frag layout, dbuf
    __shared__ __align__(16) unsigned short hBlo[2][8][64][8];
    __shared__ int tokE[2][NSEQ];
    __shared__ int lensh[NSEQ];

    {   // zero h (buffer 0) via (s,e4) mapping
        int e4 = tid >> 4;
        int kt = e4 >> 3, lb = (((e4 & 7) >> 1) << 4) | (tid & 15), j0 = (e4 & 1) * 4;
        *(ushort4*)&hBhi[0][kt][lb][j0] = make_ushort4(0, 0, 0, 0);
        *(ushort4*)&hBlo[0][kt][lb][j0] = make_ushort4(0, 0, 0, 0);
    }
    if (tid < NSEQ) {
        lensh[tid] = lens[wg * NSEQ + tid];
        tokE[0][tid] = phon[(wg * NSEQ + tid) * TPn + 0];
    }
    __syncthreads();
    int mx = 0;
#pragma unroll
    for (int i = 0; i < NSEQ; ++i) mx = max(mx, lensh[i]);
    const int mylen = lensh[s];
    float carr[4] = {0.f, 0.f, 0.f, 0.f};

    for (int t = 0; t < mx; ++t) {
        const int p = t & 1;
        if (tid < NSEQ) {   // prefetch next step's tokens into the other buffer
            int tn = (t + 1 < TPn) ? t + 1 : t;
            tokE[p ^ 1][tid] = phon[(wg * NSEQ + tid) * TPn + tn];
        }
        const int tok = tokE[p][s];
        const bf8v* Bhi = (const bf8v*)&hBhi[p][0][0][0];
        const bf8v* Blo = (const bf8v*)&hBlo[p][0][0][0];
        f4v acc[4];
#pragma unroll
        for (int tt = 0; tt < 4; ++tt) acc[tt] = (f4v)0.0f;
#pragma unroll
        for (int kt = 0; kt < 8; ++kt) {
            bf8v bh = Bhi[kt * 64 + ln];
            bf8v bl = Blo[kt * 64 + ln];
#pragma unroll
            for (int tt = 0; tt < 4; ++tt) {
                bf8v ah = Ahi[((wv * 4 + tt) * 8 + kt) * 64 + ln];
                bf8v al = Alo[((wv * 4 + tt) * 8 + kt) * 64 + ln];
                acc[tt] = __builtin_amdgcn_mfma_f32_16x16x32_bf16(ah, bh, acc[tt], 0, 0, 0);
                acc[tt] = __builtin_amdgcn_mfma_f32_16x16x32_bf16(ah, bl, acc[tt], 0, 0, 0);
                acc[tt] = __builtin_amdgcn_mfma_f32_16x16x32_bf16(al, bh, acc[tt], 0, 0, 0);
            }
        }
        // lane-local LSTM update: unit u = 16wv+4tt+q, seq s, reg i = gate i
        float hv[4];
#pragma unroll
        for (int tt = 0; tt < 4; ++tt) {
            int un = 16 * wv + 4 * tt + q;
            float4 pv = Ptu[tok * Hn + un];
            float gi = sigf(acc[tt][0] + pv.x);
            float gf = sigf(acc[tt][1] + pv.y);
            float gg = tanhf(acc[tt][2] + pv.z);
            float go = sigf(acc[tt][3] + pv.w);
            carr[tt] = fmaf(gf, carr[tt], gi * gg);
            hv[tt] = go * tanhf(carr[tt]);
        }
#pragma unroll
        for (int tt = 0; tt < 4; ++tt) {   // write h into other hB buffer
            int un = 16 * wv + 4 * tt + q;
            int kt = un >> 5, kk = un & 31;
            int lb = ((kk >> 3) << 4) | s, j = kk & 7;
            unsigned short h = bf_hi(hv[tt]);
            hBhi[p ^ 1][kt][lb][j] = h;
            hBlo[p ^ 1][kt][lb][j] = bf_hi(hv[tt] - bf_f(h));
        }
        if (t == mylen - 1) {
#pragma unroll
            for (int tt = 0; tt < 4; ++tt)
                h0dec[(wg * NSEQ + s) * Hn + 16 * wv + 4 * tt + q] = hv[tt];
        }
        __syncthreads();   // hB[p^1] complete; also fences next iter's tokE/hB writes
    }
}

// ---------------- decoder ----------------
__global__ __launch_bounds__(NT) void dec_kernel(
    const bf8v* __restrict__ Ahi, const bf8v* __restrict__ Alo,
    const bf8v* __restrict__ FAhi, const bf8v* __restrict__ FAlo,
    const float4* __restrict__ Ptu, const float* __restrict__ fcb,
    const float* __restrict__ h0dec, const int* __restrict__ sosp,
    float* __restrict__ out) {
    const int tid = threadIdx.x, wg = blockIdx.x;
    const int ln = tid & 63, wv = tid >> 6;
    const int q = ln >> 4, s = ln & 15;
    __shared__ __align__(16) unsigned short hBhi[2][8][64][8];
    __shared__ __align__(16) unsigned short hBlo[2][8][64][8];
    __shared__ int toks[NSEQ];
    __shared__ unsigned long long kex[NSEQ][16];

    {   // load h0 into hB[0] via (s,e4) mapping
        const int s_i = tid & 15, e4 = tid >> 4;
        float4 h0 = *(const float4*)&h0dec[(wg * NSEQ + s_i) * Hn + e4 * 4];
        float hv4[4] = {h0.x, h0.y, h0.z, h0.w};
        int kt = e4 >> 3, lb = (((e4 & 7) >> 1) << 4) | s_i, j0 = (e4 & 1) * 4;
        ushort4 uh, ul;
        unsigned short* uhp = (unsigned short*)&uh;
        unsigned short* ulp = (unsigned short*)&ul;
#pragma unroll
        for (int i = 0; i < 4; ++i) {
            uhp[i] = bf_hi(hv4[i]);
            ulp[i] = bf_hi(hv4[i] - bf_f(uhp[i]));
        }
        *(ushort4*)&hBhi[0][kt][lb][j0] = uh;
        *(ushort4*)&hBlo[0][kt][lb][j0] = ul;
    }
    if (tid < NSEQ) toks[tid] = sosp[0];
    const float4 fcb4 = ((const float4*)fcb)[wv * 4 + q];  // v = 16wv+4q+i
    float carr[4] = {0.f, 0.f, 0.f, 0.f};
    __syncthreads();

    bf8v bh[8];   // cached hi B-frags; invariant: holds frags of hB[t&1] at loop top
#pragma unroll
    for (int kt = 0; kt < 8; ++kt) bh[kt] = ((const bf8v*)&hBhi[0][0][0][0])[kt * 64 + ln];

    for (int t = 0; t < TPn; ++t) {
        const int p = t & 1;
        const bf8v* BloP = (const bf8v*)&hBlo[p][0][0][0];
        const int tok = toks[s];
        f4v acc[4];
#pragma unroll
        for (int tt = 0; tt < 4; ++tt) acc[tt] = (f4v)0.0f;
#pragma unroll
        for (int kt = 0; kt < 8; ++kt) {
            bf8v bl = BloP[kt * 64 + ln];
#pragma unroll
            for (int tt = 0; tt < 4; ++tt) {
                bf8v ah = Ahi[((wv * 4 + tt) * 8 + kt) * 64 + ln];
                bf8v al = Alo[((wv * 4 + tt) * 8 + kt) * 64 + ln];
                acc[tt] = __builtin_amdgcn_mfma_f32_16x16x32_bf16(ah, bh[kt], acc[tt], 0, 0, 0);
                acc[tt] = __builtin_amdgcn_mfma_f32_16x16x32_bf16(ah, bl, acc[tt], 0, 0, 0);
                acc[tt] = __builtin_amdgcn_mfma_f32_16x16x32_bf16(al, bh[kt], acc[tt], 0, 0, 0);
            }
        }
        float hv[4];
#pragma unroll
        for (int tt = 0; tt < 4; ++tt) {
            int un = 16 * wv + 4 * tt + q;
            float4 pv = Ptu[tok * Hn + un];
            float gi = sigf(acc[tt][0] + pv.x);
            float gf = sigf(acc[tt][1] + pv.y);
            float gg = tanhf(acc[tt][2] + pv.z);
            float go = sigf(acc[tt][3] + pv.w);
            carr[tt] = fmaf(gf, carr[tt], gi * gg);
            hv[tt] = go * tanhf(carr[tt]);
        }
#pragma unroll
        for (int tt = 0; tt < 4; ++tt) {
            int un = 16 * wv + 4 * tt + q;
            int kt = un >> 5, kk = un & 31;
            int lb = ((kk >> 3) << 4) | s, j = kk & 7;
            unsigned short h = bf_hi(hv[tt]);
            hBhi[p ^ 1][kt][lb][j] = h;
            hBlo[p ^ 1][kt][lb][j] = bf_hi(hv[tt] - bf_f(h));
        }
        __syncthreads();   // new h complete

        // fc: scores[v=16wv+4q+i][s], A=fcW frags, B=new h; also refresh bh cache
        const bf8v* BhiN = (const bf8v*)&hBhi[p ^ 1][0][0][0];
        const bf8v* BloN = (const bf8v*)&hBlo[p ^ 1][0][0][0];
        f4v sacc = (f4v)0.0f;
#pragma unroll
        for (int kt = 0; kt < 8; ++kt) {
            bh[kt] = BhiN[kt * 64 + ln];
            bf8v bl = BloN[kt * 64 + ln];
            bf8v ah = FAhi[(wv * 8 + kt) * 64 + ln];
            bf8v al = FAlo[(wv * 8 + kt) * 64 + ln];
            sacc = __builtin_amdgcn_mfma_f32_16x16x32_bf16(ah, bh[kt], sacc, 0, 0, 0);
            sacc = __builtin_amdgcn_mfma_f32_16x16x32_bf16(ah, bl, sacc, 0, 0, 0);
            sacc = __builtin_amdgcn_mfma_f32_16x16x32_bf16(al, bh[kt], sacc, 0, 0, 0);
        }
        float sc[4];
        unsigned long long key = 0;
#pragma unroll
        for (int i = 0; i < 4; ++i) {
            sc[i] = sacc[i] + fcb4[i];
            unsigned long long kk = amax_key(sc[i], 16 * wv + 4 * q + i);
            key = kk > key ? kk : key;
        }
        *(float4*)&out[((long)(wg * NSEQ + s) * TPn + t) * Vn + 16 * wv + 4 * q] =
            make_float4(sc[0], sc[1], sc[2], sc[3]);
        {
            unsigned long long o = __shfl_xor(key, 16, 64); key = o > key ? o : key;
            o = __shfl_xor(key, 32, 64); key = o > key ? o : key;
        }
        if (ln < 16) kex[ln][wv] = key;   // ln<16 => ln==s
        __syncthreads();
        if (tid < NSEQ) {
            unsigned long long kk = kex[tid][0];
#pragma unroll
            for (int w = 1; w < 16; ++w) kk = (kex[tid][w] > kk) ? kex[tid][w] : kk;
            toks[tid] = (Vn - 1) - (int)(kk & 0xffffffffu);
        }
        __syncthreads();
    }
}

// ---------------- launch ----------------
extern "C" void kernel_launch(void* const* d_in, const int* in_sizes, int n_in,
                              void* d_out, int out_size, void* d_ws, size_t ws_size,
                              hipStream_t stream) {
    const int*   phon = (const int*)d_in[0];
    const int*   lens = (const int*)d_in[1];
    const float* emb  = (const float*)d_in[2];
    const float* eWih = (const float*)d_in[3];
    const float* eWhh = (const float*)d_in[4];
    const float* ebih = (const float*)d_in[5];
    const float* ebhh = (const float*)d_in[6];
    const float* dWih = (const float*)d_in[7];
    const float* dWhh = (const float*)d_in[8];
    const float* dbih = (const float*)d_in[9];
    const float* dbhh = (const float*)d_in[10];
    const float* fcW  = (const float*)d_in[11];
    const float* fcb  = (const float*)d_in[12];
    const int*   sos  = (const int*)d_in[13];
    float* out = (float*)d_out;

    float4*         Ptu_e = (float4*)d_ws;                        // 65536 f4 = 1 MB
    float4*         Ptu_d = Ptu_e + 65536;                        // 1 MB
    unsigned short* WhiE  = (unsigned short*)(Ptu_d + 65536);     // 262144 us = 512 KB
    unsigned short* WloE  = WhiE + 262144;                        // 512 KB
    unsigned short* WhiD  = WloE + 262144;                        // 512 KB
    unsigned short* WloD  = WhiD + 262144;                        // 512 KB
    unsigned short* Fhi   = WloD + 262144;                        // 65536 us = 128 KB
    unsigned short* Flo   = Fhi + 65536;                          // 128 KB
    float*          h0d   = (float*)(Flo + 65536);                // 2048*256 f = 2 MB

    make_ptab<<<256, 256, 0, stream>>>(Ptu_e, emb, eWih, ebih, ebhh);
    make_ptab<<<256, 256, 0, stream>>>(Ptu_d, emb, dWih, dbih, dbhh);
    pack_w<<<1024, 256, 0, stream>>>(WhiE, WloE, eWhh);
    pack_w<<<1024, 256, 0, stream>>>(WhiD, WloD, dWhh);
    pack_fcw<<<256, 256, 0, stream>>>(Fhi, Flo, fcW);
    enc_kernel<<<NWG, NT, 0, stream>>>((const bf8v*)WhiE, (const bf8v*)WloE,
                                       Ptu_e, phon, lens, h0d);
    dec_kernel<<<NWG, NT, 0, stream>>>((const bf8v*)WhiD, (const bf8v*)WloD,
                                       (const bf8v*)Fhi, (const bf8v*)Flo,
                                       Ptu_d, fcb, h0d, sos, out);
}